// Round 7
// baseline (296.369 us; speedup 1.0000x reference)
//
#include <hip/hip_runtime.h>
#include <hip/hip_bf16.h>
#include <stdint.h>
#include <stddef.h>

using u32 = unsigned int;
using u16 = unsigned short;

typedef short bf16x8 __attribute__((ext_vector_type(8)));
typedef _Float16 f16x8 __attribute__((ext_vector_type(8)));
typedef float f32x4 __attribute__((ext_vector_type(4)));
typedef u32  u32x4 __attribute__((ext_vector_type(4)));
typedef u32  u32x2 __attribute__((ext_vector_type(2)));

// 0.25 (1/sqrt(C)) * 0.5 (k-dup comp) * log2(e)  — folded into rbuf
#define RSCALE 0.18033688011112042f

__device__ __forceinline__ u16 f2bf(float f) {
  u32 u = __builtin_bit_cast(u32, f);
  u32 r = (u + 0x7FFFu + ((u >> 16) & 1u)) >> 16;   // RNE
  return (u16)r;
}

__device__ __forceinline__ u32 pkh(float a, float b) {
  return __builtin_bit_cast(u32, __builtin_amdgcn_cvt_pkrtz(a, b));
}

// ---------------------------------------------------------------- repack ----
__global__ __launch_bounds__(256) void repack_kernel(
    const float* wR1, const float* wT1, const float* wR2, const float* wT2,
    const float* bR1, const float* gR, const float* betR, const float* mR, const float* vR,
    const float* bT1, const float* gT, const float* betT, const float* mT, const float* vT,
    const float* bR2, const float* bT2,
    u16* wb1, u16* wb2, float* scale1, float* shift1, float* biasC)
{
  if (blockIdx.x == 2592) {
    int t = threadIdx.x;
    float g, v, be, mm, bb;
    if (t < 128) { g = gR[t]; v = vR[t]; be = betR[t]; mm = mR[t]; bb = bR1[t]; }
    else         { g = gT[t-128]; v = vT[t-128]; be = betT[t-128]; mm = mT[t-128]; bb = bT1[t-128]; }
    float sc = g * rsqrtf(v + 1e-5f);
    scale1[t] = sc;
    shift1[t] = (bb - mm) * sc + be;
    biasC[t] = bR2[t];
    if (t < 64) biasC[256 + t] = (t < 48) ? bT2[t] : 0.0f;
    return;
  }
  int idx = blockIdx.x * 256 + threadIdx.x;
  if (idx < 294912) {
    int oc = idx / 1152, k = idx - oc * 1152;
    int tap = k >> 7, ic = k & 127;
    float w = (oc < 128) ? wR1[(oc * 128 + ic) * 9 + tap]
                         : wT1[((oc - 128) * 128 + ic) * 9 + tap];
    wb1[idx] = f2bf(w);
  } else {
    int r2 = idx - 294912;
    int oc = r2 / 1152, k = r2 - oc * 1152;
    int tap = k >> 7, ic = k & 127;
    float w;
    if (oc < 256)            w = wR2[(oc * 128 + ic) * 9 + tap];
    else if (oc - 256 < 48)  w = wT2[((oc - 256) * 128 + ic) * 9 + tap];
    else                     w = 0.0f;
    wb2[r2] = f2bf(w);
  }
}

// ------------------------------------------------------ NCHW -> NHWC bf16 ---
__global__ __launch_bounds__(256) void transpose_kernel(const float* feat, u16* feat_t)
{
  __shared__ float tile[128 * 33];
  int b = blockIdx.x >> 5, y = blockIdx.x & 31;
  int t = threadIdx.x;
  const float* src = feat + (size_t)(b * 128) * 1024 + y * 32;
#pragma unroll
  for (int q = 0; q < 16; q++) {
    int idx = q * 256 + t;
    int ic = idx >> 5, x = idx & 31;
    tile[ic * 33 + x] = src[(size_t)ic * 1024 + x];
  }
  __syncthreads();
  u16* dst = feat_t + (size_t)((b * 32 + y) * 32) * 128;
#pragma unroll
  for (int q = 0; q < 16; q++) {
    int idx = q * 256 + t;
    int x = idx >> 7, ic = idx & 127;
    dst[x * 128 + ic] = f2bf(tile[ic * 33 + x]);
  }
}

// -------------------------------------------- implicit-im2col conv GEMM ----
template <int SRCC, int EPI>
__global__ __launch_bounds__(256) void conv_gemm_kernel(
    const u16* __restrict__ src, const u16* __restrict__ Bt,
    u16* __restrict__ out0, float* __restrict__ out1,
    const float* __restrict__ c0, const float* __restrict__ c1)
{
  __shared__ u16 As[4 * 128 * 8];
  __shared__ u16 Bs[4 * 64 * 8];
  int t = threadIdx.x;
  int lane = t & 63, wid = t >> 6;
  int wm = wid >> 1, wn = wid & 1;
  int Mbase = blockIdx.x * 128, Nbase = blockIdx.y * 64;
  int icOff = (EPI == 1 && blockIdx.y == 4) ? 128 : 0;

  int rA = t >> 2, kc = t & 3;
  int p0 = Mbase + rA, p1 = p0 + 64;
  int y0 = (p0 >> 5) & 31, x0 = p0 & 31;
  int y1 = (p1 >> 5) & 31, x1 = p1 & 31;
  const u16* aSrc0 = src + (size_t)p0 * SRCC + icOff + kc * 8;
  const u16* aSrc1 = src + (size_t)p1 * SRCC + icOff + kc * 8;
  const u16* bSrc  = Bt + (size_t)(Nbase + rA) * 1152 + kc * 8;
  u16* aDst0 = &As[kc * 1024 + rA * 8];
  u16* aDst1 = &As[kc * 1024 + (rA + 64) * 8];
  u16* bDst  = &Bs[kc * 512 + rA * 8];

  u32x4 v0, v1, vb;
  auto LOADK = [&](int kt) {
    int tap = kt >> 2;
    int dy = tap / 3 - 1, dx = tap - (tap / 3) * 3 - 1;
    int aoff = (dy * 32 + dx) * SRCC + (kt & 3) * 32;
    u32x4 z = {};
    v0 = z; v1 = z;
    if ((u32)(y0 + dy) < 32u && (u32)(x0 + dx) < 32u)
      v0 = *reinterpret_cast<const u32x4*>(aSrc0 + (ptrdiff_t)aoff);
    if ((u32)(y1 + dy) < 32u && (u32)(x1 + dx) < 32u)
      v1 = *reinterpret_cast<const u32x4*>(aSrc1 + (ptrdiff_t)aoff);
    vb = *reinterpret_cast<const u32x4*>(bSrc + kt * 32);
  };

  f32x4 acc[4][2] = {};
  LOADK(0);
  int L = lane & 15, qs = lane >> 4;
  for (int kt = 0; kt < 36; kt++) {
    __syncthreads();
    *reinterpret_cast<u32x4*>(aDst0) = v0;
    *reinterpret_cast<u32x4*>(aDst1) = v1;
    *reinterpret_cast<u32x4*>(bDst)  = vb;
    if (kt < 35) LOADK(kt + 1);
    __syncthreads();
    bf16x8 af[4], bfr2[2];
#pragma unroll
    for (int mt = 0; mt < 4; mt++)
      af[mt] = *reinterpret_cast<const bf16x8*>(&As[qs * 1024 + (wm * 64 + mt * 16 + L) * 8]);
#pragma unroll
    for (int nt = 0; nt < 2; nt++)
      bfr2[nt] = *reinterpret_cast<const bf16x8*>(&Bs[qs * 512 + (wn * 32 + nt * 16 + L) * 8]);
#pragma unroll
    for (int mt = 0; mt < 4; mt++)
#pragma unroll
      for (int nt = 0; nt < 2; nt++)
        acc[mt][nt] = __builtin_amdgcn_mfma_f32_16x16x32_bf16(af[mt], bfr2[nt], acc[mt][nt], 0, 0, 0);
  }
#pragma unroll
  for (int mt = 0; mt < 4; mt++) {
#pragma unroll
    for (int nt = 0; nt < 2; nt++) {
      int col = Nbase + wn * 32 + nt * 16 + (lane & 15);
#pragma unroll
      for (int r = 0; r < 4; r++) {
        int rowp = Mbase + wm * 64 + mt * 16 + (lane >> 4) * 4 + r;
        float v = acc[mt][nt][r];
        if (EPI == 0) {
          float yv = v * c0[col] + c1[col];
          float h = yv / (1.0f + __expf(-yv));
          out0[(size_t)rowp * 256 + col] = f2bf(h);
        } else {
          float rv = v + c0[col];
          if (col < 256) {
            reinterpret_cast<_Float16*>(out0)[(size_t)rowp * 256 + (col & 15) * 16 + (col >> 4)] =
                (_Float16)(rv * RSCALE);
          } else {
            int cT = col - 256;
            if (cT < 48) out1[(size_t)rowp * 64 + (cT & 15) * 4 + (cT >> 4)] = rv;
            else         out1[(size_t)rowp * 64 + (cT & 15) * 4 + 3] = 0.0f;
          }
        }
      }
    }
  }
}

// ------------------------------------------------------------- attention ----
// 4-patch pipelined block: grid 8b x 31i x 8jg, block handles j=jg*4..+3
// (clamped at 30; duplicate patch rewrites identical values - benign).
// Double-buffered LDS (f16 f-tile + PV t-table) and registers; next patch's
// global loads are issued before the barrier, consumed after compute (T14).
// QK^T swapped (lane holds scores for px=nl); PV + denominator via MFMA with
// logical-color permutation and ones-column (c=3) in the t-table.
__global__ __launch_bounds__(256) void attn_kernel(
    const float* __restrict__ f, const _Float16* __restrict__ rbuf,
    const float4* __restrict__ tbuf, float* __restrict__ out)
{
  const size_t cs = (size_t)496 * 496;
  __shared__ u16 fl[2][4096];
  __shared__ u16 tl[2][1024];
  int blk = blockIdx.x;
  int b = blk / 248, rem = blk - b * 248;
  int i = rem >> 3, jg = rem & 7;
  int t = threadIdx.x;
  int lane = t & 63, w = t >> 6;
  int q = lane >> 4, nl = lane & 15;

  // staging roles
  int a = t >> 5, spy = (t >> 1) & 15, half = t & 1;   // f: ch-pair, row, half
  int tc = t & 15, lq = t >> 4;                        // t-table: col c, L-quad

  float4 fr[2][4];
  f16x8  bq[2][4];
  float  tv[2][4];

  auto LOADR = [&](int sl, int j) {
    const float* fb = f + ((size_t)b * 16 + 2 * a) * cs
                        + (size_t)(i * 16 + spy) * 496 + j * 16 + half * 8;
    fr[sl][0] = *reinterpret_cast<const float4*>(fb);
    fr[sl][1] = *reinterpret_cast<const float4*>(fb + 4);
    fr[sl][2] = *reinterpret_cast<const float4*>(fb + cs);
    fr[sl][3] = *reinterpret_cast<const float4*>(fb + cs + 4);
#pragma unroll
    for (int g = 0; g < 4; g++) {
      int ii = i + (g & 1), jj = j + (g >> 1);
      int pix = (b * 32 + ii) * 32 + jj;
      bq[sl][g] = *reinterpret_cast<const f16x8*>(rbuf + (size_t)pix * 256 + nl * 16 + (q & 1) * 8);
    }
#pragma unroll
    for (int e2 = 0; e2 < 4; e2++) {
      int l4 = lq * 4 + e2;
      float vv = 0.0f;
      if (tc == 3) vv = 1.0f;
      else if (tc < 3) {
        int wcol = ((l4 >> 3) & 3) * 4 + (l4 & 3);
        int g = (l4 >> 5) * 2 + ((l4 >> 2) & 1);
        int ii = i + (g & 1), jj = j + (g >> 1);
        int pix = (b * 32 + ii) * 32 + jj;
        vv = reinterpret_cast<const float*>(&tbuf[(size_t)pix * 16 + wcol])[tc];
      }
      tv[sl][e2] = vv;
    }
  };

  auto WRITELDS = [&](int sl) {
    float4 A0 = fr[sl][0], A1 = fr[sl][1], A2 = fr[sl][2], A3 = fr[sl][3];
    float lo[8] = {A0.x, A0.y, A0.z, A0.w, A1.x, A1.y, A1.z, A1.w};
    float hi[8] = {A2.x, A2.y, A2.z, A2.w, A3.x, A3.y, A3.z, A3.w};
    int base = spy * 256 + (a >> 2) * 128 + (a & 3) * 2;
#pragma unroll
    for (int p2 = 0; p2 < 8; p2++) {
      int px = half * 8 + p2;
      *reinterpret_cast<u32*>(&fl[sl][base + ((px ^ spy) * 8)]) = pkh(lo[p2], hi[p2]);
    }
    u32x2 pp = { pkh(tv[sl][0], tv[sl][1]), pkh(tv[sl][2], tv[sl][3]) };
    *reinterpret_cast<u32x2*>(&tl[sl][tc * 64 + lq * 4]) = pp;
  };

  int jb = jg * 4;
  LOADR(0, jb);
#pragma unroll
  for (int p = 0; p < 4; p++) {
    int sl = p & 1;
    int j = jb + p; if (j > 30) j = 30;
    WRITELDS(sl);
    if (p < 3) { int jn = jb + p + 1; if (jn > 30) jn = 30; LOADR((p + 1) & 1, jn); }
    __syncthreads();

    f16x8 pb1 = *reinterpret_cast<const f16x8*>(&tl[sl][nl * 64 + q * 8]);
    f16x8 pb2 = *reinterpret_cast<const f16x8*>(&tl[sl][nl * 64 + 32 + q * 8]);
#pragma unroll
    for (int mt = 0; mt < 4; mt++) {
      int py = w * 4 + mt;
      f16x8 afr = *reinterpret_cast<const f16x8*>(
          &fl[sl][py * 256 + (q & 1) * 128 + ((nl ^ py) & 15) * 8]);
      f32x4 z = {0.f, 0.f, 0.f, 0.f};
      f32x4 s0 = __builtin_amdgcn_mfma_f32_16x16x32_f16(bq[sl][0], afr, z, 0, 0, 0);
      f32x4 s1 = __builtin_amdgcn_mfma_f32_16x16x32_f16(bq[sl][1], afr, z, 0, 0, 0);
      f32x4 s2 = __builtin_amdgcn_mfma_f32_16x16x32_f16(bq[sl][2], afr, z, 0, 0, 0);
      f32x4 s3 = __builtin_amdgcn_mfma_f32_16x16x32_f16(bq[sl][3], afr, z, 0, 0, 0);

      float e0[4], e1[4], e2[4], e3[4];
#pragma unroll
      for (int r = 0; r < 4; r++) {
        e0[r] = exp2f(s0[r]); e1[r] = exp2f(s1[r]);
        e2[r] = exp2f(s2[r]); e3[r] = exp2f(s3[r]);
      }
      u32x4 A1u = { pkh(e0[0], e0[1]), pkh(e0[2], e0[3]),
                    pkh(e1[0], e1[1]), pkh(e1[2], e1[3]) };
      u32x4 A2u = { pkh(e2[0], e2[1]), pkh(e2[2], e2[3]),
                    pkh(e3[0], e3[1]), pkh(e3[2], e3[3]) };
      f16x8 A1 = __builtin_bit_cast(f16x8, A1u);
      f16x8 A2 = __builtin_bit_cast(f16x8, A2u);

      f32x4 d = __builtin_amdgcn_mfma_f32_16x16x32_f16(A1, pb1, z, 0, 0, 0);
      d = __builtin_amdgcn_mfma_f32_16x16x32_f16(A2, pb2, d, 0, 0, 0);

      int src = (lane & 48) | 3;          // lane (q,3) holds l[px=q*4+r]
      float l0 = __shfl(d[0], src), l1 = __shfl(d[1], src),
            l2 = __shfl(d[2], src), l3 = __shfl(d[3], src);
      if (nl < 3) {
        float4 o;
        o.x = d[0] * __builtin_amdgcn_rcpf(l0);
        o.y = d[1] * __builtin_amdgcn_rcpf(l1);
        o.z = d[2] * __builtin_amdgcn_rcpf(l2);
        o.w = d[3] * __builtin_amdgcn_rcpf(l3);
        *reinterpret_cast<float4*>(out + ((size_t)b * 3 + nl) * cs
                                   + (size_t)(i * 16 + py) * 496 + j * 16 + q * 4) = o;
      }
    }
  }
}

// ----------------------------------------------------------------- launch ---
extern "C" void kernel_launch(void* const* d_in, const int* in_sizes, int n_in,
                              void* d_out, int out_size, void* d_ws, size_t ws_size,
                              hipStream_t stream)
{
  const float* f    = (const float*)d_in[0];
  const float* feats= (const float*)d_in[1];
  const float* wR1  = (const float*)d_in[2];
  const float* bR1  = (const float*)d_in[3];
  const float* gR   = (const float*)d_in[4];
  const float* betR = (const float*)d_in[5];
  const float* mR   = (const float*)d_in[6];
  const float* vR   = (const float*)d_in[7];
  const float* wR2  = (const float*)d_in[8];
  const float* bR2  = (const float*)d_in[9];
  const float* wT1  = (const float*)d_in[10];
  const float* bT1  = (const float*)d_in[11];
  const float* gT   = (const float*)d_in[12];
  const float* betT = (const float*)d_in[13];
  const float* mT   = (const float*)d_in[14];
  const float* vT   = (const float*)d_in[15];
  const float* wT2  = (const float*)d_in[16];
  const float* bT2  = (const float*)d_in[17];
  (void)in_sizes; (void)n_in; (void)out_size; (void)ws_size;

  char* ws = (char*)d_ws;
  u16*   wb1    = (u16*)(ws + 0);              // 256*1152*2 = 589824
  u16*   wb2    = (u16*)(ws + 589824);         // 320*1152*2 = 737280
  float* scale1 = (float*)(ws + 1327104);      // 256 f
  float* shift1 = scale1 + 256;
  float* biasC  = scale1 + 512;                // 320 f
  u16*   feat_t = (u16*)(ws + 1330432);        // 8*1024*128*2 = 2097152
  u16*   hbuf   = (u16*)(ws + 3427584);        // 8192*256*2   = 4194304
  u16*   rbuf16 = (u16*)(ws + 7621888);        // 8192*256*2   = 4194304 (f16)
  float* tbuf   = (float*)(ws + 11816192);     // 8192*64*4    = 2097152

  repack_kernel<<<dim3(2593), dim3(256), 0, stream>>>(
      wR1, wT1, wR2, wT2, bR1, gR, betR, mR, vR, bT1, gT, betT, mT, vT,
      bR2, bT2, wb1, wb2, scale1, shift1, biasC);

  transpose_kernel<<<dim3(256), dim3(256), 0, stream>>>(feats, feat_t);

  conv_gemm_kernel<128, 0><<<dim3(64, 4), dim3(256), 0, stream>>>(
      feat_t, wb1, hbuf, nullptr, scale1, shift1);

  conv_gemm_kernel<256, 1><<<dim3(64, 5), dim3(256), 0, stream>>>(
      hbuf, wb2, rbuf16, tbuf, biasC, nullptr);

  attn_kernel<<<dim3(1984), dim3(256), 0, stream>>>(
      f, (const _Float16*)rbuf16, (const float4*)tbuf, (float*)d_out);
}

// Round 9
// 289.547 us; speedup vs baseline: 1.0236x; 1.0236x over previous
//
#include <hip/hip_runtime.h>
#include <hip/hip_bf16.h>
#include <stdint.h>
#include <stddef.h>

using u32 = unsigned int;
using u16 = unsigned short;

typedef short bf16x8 __attribute__((ext_vector_type(8)));
typedef _Float16 f16x8 __attribute__((ext_vector_type(8)));
typedef float f32x4 __attribute__((ext_vector_type(4)));
typedef u32  u32x4 __attribute__((ext_vector_type(4)));
typedef u32  u32x2 __attribute__((ext_vector_type(2)));

// 0.25 (1/sqrt(C)) * 0.5 (k-dup comp) * log2(e)  — folded into rbuf
#define RSCALE 0.18033688011112042f

__device__ __forceinline__ u16 f2bf(float f) {
  u32 u = __builtin_bit_cast(u32, f);
  u32 r = (u + 0x7FFFu + ((u >> 16) & 1u)) >> 16;   // RNE
  return (u16)r;
}

__device__ __forceinline__ u32 pkh(float a, float b) {
  return __builtin_bit_cast(u32, __builtin_amdgcn_cvt_pkrtz(a, b));
}

// ---------------------------------------------------------------- repack ----
__global__ __launch_bounds__(256) void repack_kernel(
    const float* wR1, const float* wT1, const float* wR2, const float* wT2,
    const float* bR1, const float* gR, const float* betR, const float* mR, const float* vR,
    const float* bT1, const float* gT, const float* betT, const float* mT, const float* vT,
    const float* bR2, const float* bT2,
    u16* wb1, u16* wb2, float* scale1, float* shift1, float* biasC)
{
  if (blockIdx.x == 2592) {
    int t = threadIdx.x;
    float g, v, be, mm, bb;
    if (t < 128) { g = gR[t]; v = vR[t]; be = betR[t]; mm = mR[t]; bb = bR1[t]; }
    else         { g = gT[t-128]; v = vT[t-128]; be = betT[t-128]; mm = mT[t-128]; bb = bT1[t-128]; }
    float sc = g * rsqrtf(v + 1e-5f);
    scale1[t] = sc;
    shift1[t] = (bb - mm) * sc + be;
    biasC[t] = bR2[t];
    if (t < 64) biasC[256 + t] = (t < 48) ? bT2[t] : 0.0f;
    return;
  }
  int idx = blockIdx.x * 256 + threadIdx.x;
  if (idx < 294912) {
    int oc = idx / 1152, k = idx - oc * 1152;
    int tap = k >> 7, ic = k & 127;
    float w = (oc < 128) ? wR1[(oc * 128 + ic) * 9 + tap]
                         : wT1[((oc - 128) * 128 + ic) * 9 + tap];
    wb1[idx] = f2bf(w);
  } else {
    int r2 = idx - 294912;
    int oc = r2 / 1152, k = r2 - oc * 1152;
    int tap = k >> 7, ic = k & 127;
    float w;
    if (oc < 256)            w = wR2[(oc * 128 + ic) * 9 + tap];
    else if (oc - 256 < 48)  w = wT2[((oc - 256) * 128 + ic) * 9 + tap];
    else                     w = 0.0f;
    wb2[r2] = f2bf(w);
  }
}

// ------------------------------------------------------ NCHW -> NHWC bf16 ---
__global__ __launch_bounds__(256) void transpose_kernel(const float* feat, u16* feat_t)
{
  __shared__ float tile[128 * 33];
  int b = blockIdx.x >> 5, y = blockIdx.x & 31;
  int t = threadIdx.x;
  const float* src = feat + (size_t)(b * 128) * 1024 + y * 32;
#pragma unroll
  for (int q = 0; q < 16; q++) {
    int idx = q * 256 + t;
    int ic = idx >> 5, x = idx & 31;
    tile[ic * 33 + x] = src[(size_t)ic * 1024 + x];
  }
  __syncthreads();
  u16* dst = feat_t + (size_t)((b * 32 + y) * 32) * 128;
#pragma unroll
  for (int q = 0; q < 16; q++) {
    int idx = q * 256 + t;
    int x = idx >> 7, ic = idx & 127;
    dst[x * 128 + ic] = f2bf(tile[ic * 33 + x]);
  }
}

// -------------------------------------------- implicit-im2col conv GEMM ----
template <int SRCC, int EPI>
__global__ __launch_bounds__(256) void conv_gemm_kernel(
    const u16* __restrict__ src, const u16* __restrict__ Bt,
    u16* __restrict__ out0, float* __restrict__ out1,
    const float* __restrict__ c0, const float* __restrict__ c1)
{
  __shared__ u16 As[4 * 128 * 8];
  __shared__ u16 Bs[4 * 64 * 8];
  int t = threadIdx.x;
  int lane = t & 63, wid = t >> 6;
  int wm = wid >> 1, wn = wid & 1;
  int Mbase = blockIdx.x * 128, Nbase = blockIdx.y * 64;
  int icOff = (EPI == 1 && blockIdx.y == 4) ? 128 : 0;

  int rA = t >> 2, kc = t & 3;
  int p0 = Mbase + rA, p1 = p0 + 64;
  int y0 = (p0 >> 5) & 31, x0 = p0 & 31;
  int y1 = (p1 >> 5) & 31, x1 = p1 & 31;
  const u16* aSrc0 = src + (size_t)p0 * SRCC + icOff + kc * 8;
  const u16* aSrc1 = src + (size_t)p1 * SRCC + icOff + kc * 8;
  const u16* bSrc  = Bt + (size_t)(Nbase + rA) * 1152 + kc * 8;
  u16* aDst0 = &As[kc * 1024 + rA * 8];
  u16* aDst1 = &As[kc * 1024 + (rA + 64) * 8];
  u16* bDst  = &Bs[kc * 512 + rA * 8];

  u32x4 v0, v1, vb;
  auto LOADK = [&](int kt) {
    int tap = kt >> 2;
    int dy = tap / 3 - 1, dx = tap - (tap / 3) * 3 - 1;
    int aoff = (dy * 32 + dx) * SRCC + (kt & 3) * 32;
    u32x4 z = {};
    v0 = z; v1 = z;
    if ((u32)(y0 + dy) < 32u && (u32)(x0 + dx) < 32u)
      v0 = *reinterpret_cast<const u32x4*>(aSrc0 + (ptrdiff_t)aoff);
    if ((u32)(y1 + dy) < 32u && (u32)(x1 + dx) < 32u)
      v1 = *reinterpret_cast<const u32x4*>(aSrc1 + (ptrdiff_t)aoff);
    vb = *reinterpret_cast<const u32x4*>(bSrc + kt * 32);
  };

  f32x4 acc[4][2] = {};
  LOADK(0);
  int L = lane & 15, qs = lane >> 4;
  for (int kt = 0; kt < 36; kt++) {
    __syncthreads();
    *reinterpret_cast<u32x4*>(aDst0) = v0;
    *reinterpret_cast<u32x4*>(aDst1) = v1;
    *reinterpret_cast<u32x4*>(bDst)  = vb;
    if (kt < 35) LOADK(kt + 1);
    __syncthreads();
    bf16x8 af[4], bfr2[2];
#pragma unroll
    for (int mt = 0; mt < 4; mt++)
      af[mt] = *reinterpret_cast<const bf16x8*>(&As[qs * 1024 + (wm * 64 + mt * 16 + L) * 8]);
#pragma unroll
    for (int nt = 0; nt < 2; nt++)
      bfr2[nt] = *reinterpret_cast<const bf16x8*>(&Bs[qs * 512 + (wn * 32 + nt * 16 + L) * 8]);
#pragma unroll
    for (int mt = 0; mt < 4; mt++)
#pragma unroll
      for (int nt = 0; nt < 2; nt++)
        acc[mt][nt] = __builtin_amdgcn_mfma_f32_16x16x32_bf16(af[mt], bfr2[nt], acc[mt][nt], 0, 0, 0);
  }
#pragma unroll
  for (int mt = 0; mt < 4; mt++) {
#pragma unroll
    for (int nt = 0; nt < 2; nt++) {
      int col = Nbase + wn * 32 + nt * 16 + (lane & 15);
#pragma unroll
      for (int r = 0; r < 4; r++) {
        int rowp = Mbase + wm * 64 + mt * 16 + (lane >> 4) * 4 + r;
        float v = acc[mt][nt][r];
        if (EPI == 0) {
          float yv = v * c0[col] + c1[col];
          float h = yv / (1.0f + __expf(-yv));
          out0[(size_t)rowp * 256 + col] = f2bf(h);
        } else {
          float rv = v + c0[col];
          if (col < 256) {
            reinterpret_cast<_Float16*>(out0)[(size_t)rowp * 256 + (col & 15) * 16 + (col >> 4)] =
                (_Float16)(rv * RSCALE);
          } else {
            int cT = col - 256;
            if (cT < 48) out1[(size_t)rowp * 64 + (cT & 15) * 4 + (cT >> 4)] = rv;
            else         out1[(size_t)rowp * 64 + (cT & 15) * 4 + 3] = 0.0f;
          }
        }
      }
    }
  }
}

// ------------------------------------------------------------- attention ----
// Depth-2 pipelined block, ALL pipeline state in NAMED registers (rule #20).
// Grid 8b x 31i x 16jg; block does j0=2jg, j1=min(j0+1,30) (dup at edge ok).
// Phase: load A+B upfront -> writeLDS(A,buf0) -> bar -> compute(A) ||
// (B loads in flight) -> writeLDS(B,buf1) -> bar -> compute(B).
// QK^T swapped + PV/denominator via MFMA (ones-column trick), setprio(1)
// around the MFMA+exp cluster (T5).
__device__ __forceinline__ float tload(const float4* tbuf, int tc, int lq, int e2,
                                       int b, int i, int j) {
  if (tc == 3) return 1.0f;
  if (tc > 3) return 0.0f;
  int l4 = lq * 4 + e2;
  int wcol = ((l4 >> 3) & 3) * 4 + (l4 & 3);
  int g = (l4 >> 5) * 2 + ((l4 >> 2) & 1);
  int ii = i + (g & 1), jj = j + (g >> 1);
  int pix = (b * 32 + ii) * 32 + jj;
  return reinterpret_cast<const float*>(&tbuf[(size_t)pix * 16 + wcol])[tc];
}

#define LOADP(S, JJ) do {                                                          \
  const float* fb = f + ((size_t)b * 16 + 2 * a) * cs                              \
                      + (size_t)(i * 16 + spy) * 496 + (JJ) * 16 + half * 8;       \
  fr0##S = *reinterpret_cast<const float4*>(fb);                                   \
  fr1##S = *reinterpret_cast<const float4*>(fb + 4);                               \
  fr2##S = *reinterpret_cast<const float4*>(fb + cs);                              \
  fr3##S = *reinterpret_cast<const float4*>(fb + cs + 4);                          \
  { int pixq = (b * 32 + i) * 32 + (JJ);                                           \
    bq0##S = *reinterpret_cast<const f16x8*>(rbuf + (size_t)pixq * 256 + nl * 16 + (q & 1) * 8); \
    pixq = (b * 32 + i + 1) * 32 + (JJ);                                           \
    bq1##S = *reinterpret_cast<const f16x8*>(rbuf + (size_t)pixq * 256 + nl * 16 + (q & 1) * 8); \
    pixq = (b * 32 + i) * 32 + (JJ) + 1;                                           \
    bq2##S = *reinterpret_cast<const f16x8*>(rbuf + (size_t)pixq * 256 + nl * 16 + (q & 1) * 8); \
    pixq = (b * 32 + i + 1) * 32 + (JJ) + 1;                                       \
    bq3##S = *reinterpret_cast<const f16x8*>(rbuf + (size_t)pixq * 256 + nl * 16 + (q & 1) * 8); } \
  tv0##S = tload(tbuf, tc, lq, 0, b, i, (JJ));                                     \
  tv1##S = tload(tbuf, tc, lq, 1, b, i, (JJ));                                     \
  tv2##S = tload(tbuf, tc, lq, 2, b, i, (JJ));                                     \
  tv3##S = tload(tbuf, tc, lq, 3, b, i, (JJ));                                     \
} while (0)

#define WRITELDS(S, SL) do {                                                       \
  float lo[8] = {fr0##S.x, fr0##S.y, fr0##S.z, fr0##S.w,                           \
                 fr1##S.x, fr1##S.y, fr1##S.z, fr1##S.w};                          \
  float hi[8] = {fr2##S.x, fr2##S.y, fr2##S.z, fr2##S.w,                           \
                 fr3##S.x, fr3##S.y, fr3##S.z, fr3##S.w};                          \
  int base = spy * 256 + (a >> 2) * 128 + (a & 3) * 2;                             \
  _Pragma("unroll")                                                                \
  for (int p2 = 0; p2 < 8; p2++) {                                                 \
    int px = half * 8 + p2;                                                        \
    *reinterpret_cast<u32*>(&fl[SL][base + ((px ^ spy) * 8)]) = pkh(lo[p2], hi[p2]); \
  }                                                                                \
  u32x2 pp = { pkh(tv0##S, tv1##S), pkh(tv2##S, tv3##S) };                         \
  *reinterpret_cast<u32x2*>(&tl[SL][tc * 64 + lq * 4]) = pp;                       \
} while (0)

#define COMPUTE(SL, S, JJ) do {                                                    \
  f16x8 pb1 = *reinterpret_cast<const f16x8*>(&tl[SL][nl * 64 + q * 8]);           \
  f16x8 pb2 = *reinterpret_cast<const f16x8*>(&tl[SL][nl * 64 + 32 + q * 8]);      \
  _Pragma("unroll")                                                                \
  for (int mt = 0; mt < 4; mt++) {                                                 \
    int py = w * 4 + mt;                                                           \
    f16x8 afr = *reinterpret_cast<const f16x8*>(                                   \
        &fl[SL][py * 256 + (q & 1) * 128 + ((nl ^ py) & 15) * 8]);                 \
    f32x4 z = {0.f, 0.f, 0.f, 0.f};                                                \
    __builtin_amdgcn_s_setprio(1);                                                 \
    f32x4 s0 = __builtin_amdgcn_mfma_f32_16x16x32_f16(bq0##S, afr, z, 0, 0, 0);    \
    f32x4 s1 = __builtin_amdgcn_mfma_f32_16x16x32_f16(bq1##S, afr, z, 0, 0, 0);    \
    f32x4 s2 = __builtin_amdgcn_mfma_f32_16x16x32_f16(bq2##S, afr, z, 0, 0, 0);    \
    f32x4 s3 = __builtin_amdgcn_mfma_f32_16x16x32_f16(bq3##S, afr, z, 0, 0, 0);    \
    float e0[4], e1[4], e2v[4], e3[4];                                             \
    _Pragma("unroll")                                                              \
    for (int r = 0; r < 4; r++) {                                                  \
      e0[r] = exp2f(s0[r]);  e1[r] = exp2f(s1[r]);                                 \
      e2v[r] = exp2f(s2[r]); e3[r] = exp2f(s3[r]);                                 \
    }                                                                              \
    u32x4 A1u = { pkh(e0[0], e0[1]), pkh(e0[2], e0[3]),                            \
                  pkh(e1[0], e1[1]), pkh(e1[2], e1[3]) };                          \
    u32x4 A2u = { pkh(e2v[0], e2v[1]), pkh(e2v[2], e2v[3]),                        \
                  pkh(e3[0], e3[1]), pkh(e3[2], e3[3]) };                          \
    f16x8 A1 = __builtin_bit_cast(f16x8, A1u);                                     \
    f16x8 A2 = __builtin_bit_cast(f16x8, A2u);                                     \
    f32x4 d = __builtin_amdgcn_mfma_f32_16x16x32_f16(A1, pb1, z, 0, 0, 0);         \
    d = __builtin_amdgcn_mfma_f32_16x16x32_f16(A2, pb2, d, 0, 0, 0);               \
    __builtin_amdgcn_s_setprio(0);                                                 \
    int srcl = (lane & 48) | 3;                                                    \
    float l0 = __shfl(d[0], srcl), l1 = __shfl(d[1], srcl),                        \
          l2 = __shfl(d[2], srcl), l3 = __shfl(d[3], srcl);                        \
    if (nl < 3) {                                                                  \
      float4 o;                                                                    \
      o.x = d[0] * __builtin_amdgcn_rcpf(l0);                                      \
      o.y = d[1] * __builtin_amdgcn_rcpf(l1);                                      \
      o.z = d[2] * __builtin_amdgcn_rcpf(l2);                                      \
      o.w = d[3] * __builtin_amdgcn_rcpf(l3);                                      \
      *reinterpret_cast<float4*>(out + ((size_t)b * 3 + nl) * cs                   \
                                 + (size_t)(i * 16 + py) * 496 + (JJ) * 16 + q * 4) = o; \
    }                                                                              \
  }                                                                                \
} while (0)

__global__ __launch_bounds__(256) void attn_kernel(
    const float* __restrict__ f, const _Float16* __restrict__ rbuf,
    const float4* __restrict__ tbuf, float* __restrict__ out)
{
  const size_t cs = (size_t)496 * 496;
  __shared__ u16 fl[2][4096];
  __shared__ u16 tl[2][1024];
  int blk = blockIdx.x;
  int b = blk / 496, rem = blk - b * 496;    // 31*16 = 496
  int i = rem >> 4, jg = rem & 15;
  int j0 = jg * 2;
  int j1 = (j0 + 1 > 30) ? 30 : j0 + 1;
  int t = threadIdx.x;
  int lane = t & 63, w = t >> 6;
  int q = lane >> 4, nl = lane & 15;

  // staging roles
  int a = t >> 5, spy = (t >> 1) & 15, half = t & 1;   // f: ch-pair, row, half
  int tc = t & 15, lq = t >> 4;                        // t-table: col c, L-quad

  float4 fr0A, fr1A, fr2A, fr3A, fr0B, fr1B, fr2B, fr3B;
  f16x8  bq0A, bq1A, bq2A, bq3A, bq0B, bq1B, bq2B, bq3B;
  float  tv0A, tv1A, tv2A, tv3A, tv0B, tv1B, tv2B, tv3B;

  LOADP(A, j0);
  LOADP(B, j1);
  WRITELDS(A, 0);
  __syncthreads();
  COMPUTE(0, A, j0);
  WRITELDS(B, 1);
  __syncthreads();
  COMPUTE(1, B, j1);
}

// ----------------------------------------------------------------- launch ---
extern "C" void kernel_launch(void* const* d_in, const int* in_sizes, int n_in,
                              void* d_out, int out_size, void* d_ws, size_t ws_size,
                              hipStream_t stream)
{
  const float* f    = (const float*)d_in[0];
  const float* feats= (const float*)d_in[1];
  const float* wR1  = (const float*)d_in[2];
  const float* bR1  = (const float*)d_in[3];
  const float* gR   = (const float*)d_in[4];
  const float* betR = (const float*)d_in[5];
  const float* mR   = (const float*)d_in[6];
  const float* vR   = (const float*)d_in[7];
  const float* wR2  = (const float*)d_in[8];
  const float* bR2  = (const float*)d_in[9];
  const float* wT1  = (const float*)d_in[10];
  const float* bT1  = (const float*)d_in[11];
  const float* gT   = (const float*)d_in[12];
  const float* betT = (const float*)d_in[13];
  const float* mT   = (const float*)d_in[14];
  const float* vT   = (const float*)d_in[15];
  const float* wT2  = (const float*)d_in[16];
  const float* bT2  = (const float*)d_in[17];
  (void)in_sizes; (void)n_in; (void)out_size; (void)ws_size;

  char* ws = (char*)d_ws;
  u16*   wb1    = (u16*)(ws + 0);              // 256*1152*2 = 589824
  u16*   wb2    = (u16*)(ws + 589824);         // 320*1152*2 = 737280
  float* scale1 = (float*)(ws + 1327104);      // 256 f
  float* shift1 = scale1 + 256;
  float* biasC  = scale1 + 512;                // 320 f
  u16*   feat_t = (u16*)(ws + 1330432);        // 8*1024*128*2 = 2097152
  u16*   hbuf   = (u16*)(ws + 3427584);        // 8192*256*2   = 4194304
  u16*   rbuf16 = (u16*)(ws + 7621888);        // 8192*256*2   = 4194304 (f16)
  float* tbuf   = (float*)(ws + 11816192);     // 8192*64*4    = 2097152

  repack_kernel<<<dim3(2593), dim3(256), 0, stream>>>(
      wR1, wT1, wR2, wT2, bR1, gR, betR, mR, vR, bT1, gT, betT, mT, vT,
      bR2, bT2, wb1, wb2, scale1, shift1, biasC);

  transpose_kernel<<<dim3(256), dim3(256), 0, stream>>>(feats, feat_t);

  conv_gemm_kernel<128, 0><<<dim3(64, 4), dim3(256), 0, stream>>>(
      feat_t, wb1, hbuf, nullptr, scale1, shift1);

  conv_gemm_kernel<256, 1><<<dim3(64, 5), dim3(256), 0, stream>>>(
      hbuf, wb2, rbuf16, tbuf, biasC, nullptr);

  attn_kernel<<<dim3(3968), dim3(256), 0, stream>>>(
      f, (const _Float16*)rbuf16, (const float4*)tbuf, (float*)d_out);
}